// Round 12
// baseline (77.544 us; speedup 1.0000x reference)
//
#include <hip/hip_runtime.h>
#include <stdint.h>

#define B_ 128
#define Q_ 2048
#define C_ 8
#define L_ 256
#define K_ 64
#define S_ 1985            // Q - K + 1
#define KC_ 512            // K*C

typedef short s16x8 __attribute__((ext_vector_type(8)));
typedef float f32x16 __attribute__((ext_vector_type(16)));

__device__ __forceinline__ unsigned short f2bf(float f) {
    unsigned u = __float_as_uint(f);
    u += 0x7FFFu + ((u >> 16) & 1u);        // round-to-nearest-even
    return (unsigned short)(u >> 16);
}
// monotone float -> unsigned encoding (order-preserving), for atomicMin
__device__ __forceinline__ unsigned fenc(float f) {
    unsigned u = __float_as_uint(f);
    return (u & 0x80000000u) ? ~u : (u | 0x80000000u);
}
__device__ __forceinline__ float fdec(unsigned k) {
    unsigned u = (k & 0x80000000u) ? (k ^ 0x80000000u) : ~k;
    return __uint_as_float(u);
}
__device__ __forceinline__ void async_copy16(void* lds_dst, const void* g_src) {
    __builtin_amdgcn_global_load_lds(
        (const __attribute__((address_space(1))) void*)g_src,
        (__attribute__((address_space(3))) void*)lds_dst, 16, 0, 0);
}

// ---- fused prep: ts cast+window-norms | shapelet transpose+norms | init ----
// blocks 0..127   : per-batch ts -> tsb (bf16) + extg (-wq/2 bf16 pair; -inf
//                   for invalid windows -> GEMM-side masking)
// blocks 128..191 : shapelets -> k-major shb2[chunk][col] bf16 + shsq
// blocks 192..193 : zero tsb overrun pad
// blocks 194..321 : hmin init
__global__ __launch_bounds__(256) void k_prep(const float* __restrict__ ts,
                                              const float* __restrict__ sh,
                                              uint4* __restrict__ tsb,
                                              uint4* __restrict__ shb2,
                                              float* __restrict__ shsq,
                                              unsigned* __restrict__ extg,
                                              unsigned* __restrict__ hmin) {
    __shared__ float t2[2048];
    const int bid = blockIdx.x, t = threadIdx.x;
    if (bid < 128) {
        const int b = bid;
        #pragma unroll
        for (int j = 0; j < 8; ++j) {
            int r = j * 256 + t;
            const float4* p = (const float4*)(ts + ((size_t)b * Q_ + r) * C_);
            float4 x = p[0], y = p[1];
            union { unsigned short h[8]; uint4 v; } u;
            u.h[0] = f2bf(x.x); u.h[1] = f2bf(x.y); u.h[2] = f2bf(x.z); u.h[3] = f2bf(x.w);
            u.h[4] = f2bf(y.x); u.h[5] = f2bf(y.y); u.h[6] = f2bf(y.z); u.h[7] = f2bf(y.w);
            tsb[(size_t)b * Q_ + r] = u.v;
            t2[r] = x.x*x.x + x.y*x.y + x.z*x.z + x.w*x.w
                  + y.x*y.x + y.y*y.y + y.z*y.z + y.w*y.w;
        }
        __syncthreads();
        int s0 = t * 8;
        float w = 0.f;
        if (s0 < S_) {
            #pragma unroll 16
            for (int k = 0; k < K_; ++k) w += t2[s0 + k];
        }
        #pragma unroll
        for (int j = 0; j < 8; ++j) {
            int s = s0 + j;
            unsigned word = 0x0000FF80u;              // slot0 = -inf, slot1 = 0
            if (s < S_) {
                float v = -0.5f * w;
                unsigned short hh = f2bf(v);
                float hf = __uint_as_float((unsigned)hh << 16);
                unsigned short ll = f2bf(v - hf);
                word = (unsigned)hh | ((unsigned)ll << 16);
            }
            extg[(size_t)b * Q_ + s] = word;
            if (s + K_ < Q_) w += t2[s + K_] - t2[s]; // slide window
        }
    } else if (bid < 192) {
        const int l = (bid - 128) * 4 + (t >> 6);     // shapelet index
        const int c = t & 63;                         // k16-chunk index
        const float4* p = (const float4*)(sh + (size_t)l * KC_) + c * 2;
        float4 x = p[0], y = p[1];
        union { unsigned short h[8]; uint4 v; } u;
        u.h[0] = f2bf(x.x); u.h[1] = f2bf(x.y); u.h[2] = f2bf(x.z); u.h[3] = f2bf(x.w);
        u.h[4] = f2bf(y.x); u.h[5] = f2bf(y.y); u.h[6] = f2bf(y.z); u.h[7] = f2bf(y.w);
        shb2[c * L_ + l] = u.v;                       // k-major [chunk][col]
        float ss = x.x*x.x + x.y*x.y + x.z*x.z + x.w*x.w
                 + y.x*y.x + y.y*y.y + y.z*y.z + y.w*y.w;
        #pragma unroll
        for (int off = 32; off >= 1; off >>= 1) ss += __shfl_down(ss, off, 64);
        if (c == 0) shsq[l] = ss;
    } else if (bid < 194) {
        uint4 z; z.x = z.y = z.z = z.w = 0u;
        tsb[B_ * Q_ + (bid - 192) * 256 + t] = z;
    } else {
        hmin[(bid - 194) * 256 + t] = 0xFFFFFFFFu;
    }
}

// ---- main: implicit-GEMM conv + fused min-pool; B from global/L2 ----
// grid (8, 128) = 1024 blocks (3/CU at ~155 regs). Block = 4 waves (2m x
// 2n), tile 128 rows x 128 cols, acc 2x2, 4 m-iters. LDS = A only (3 KB,
// single-buffered per iter; stage+barrier hides under other blocks).
// B-frags stream from k-major shb2 (L2-resident) on the idle VMEM pipe:
// LDS bytes/MFMA = 512 (A only) -> ~63 B/cyc, half the pipe. kk-loop
// unroll capped at 4 (R10 lesson: full unroll -> 64 loads in flight ->
// spill storm). wq + invalid-mask folded via K-extension MFMA.
__global__ __launch_bounds__(256, 3) void k_main(
    const uint4* __restrict__ tsb,        // bf16 [B][Q][C] (+512 pad rows)
    const uint4* __restrict__ shb2,       // bf16 k-major [64][256] frags
    const unsigned* __restrict__ extg,    // [B][2048] packed (-wq/2) pairs
    const float* __restrict__ shsq,       // [L]
    unsigned*    __restrict__ hmin)       // [B][L] encoded min
{
    __shared__ uint4 a_lds[192];          // 192 ts-rows x 16B = 3 KB

    const int ms   = blockIdx.x >> 1;     // 0..3
    const int nt   = blockIdx.x & 1;      // 0..1
    const int b    = blockIdx.y;
    const int m0   = ms * 512;            // 4 m-iters x 128 rows
    const int c0   = nt * 128;
    const int tid  = threadIdx.x;
    const int lane = tid & 63;
    const int wv   = tid >> 6;            // 0..3
    const int l31  = lane & 31;
    const int hi   = lane >> 5;
    const int wm   = wv >> 1;             // 0..1 row group of 64
    const int wn   = wv & 1;              // 0..1 col group of 64

    #define STAGE_A(mi_)                                                       \
        if (tid < 192)                                                         \
            async_copy16((char*)a_lds + tid * 16,                              \
                         (const char*)(tsb + (size_t)b * Q_ + m0 + (mi_) * 128)\
                         + tid * 16);

    const f32x16 fz = {0.f,0.f,0.f,0.f,0.f,0.f,0.f,0.f,
                       0.f,0.f,0.f,0.f,0.f,0.f,0.f,0.f};
    const float inf = __builtin_inff();
    float rm0 = inf, rm1 = inf;           // cols c0+wn*64+l31 / +32

    const char* ab    = (const char*)a_lds;
    const int   arow  = wm * 64 + l31 + hi;
    const char* bbase = (const char*)shb2 + (size_t)(c0 + wn * 64 + l31) * 16;

    union UU { unsigned u[4]; s16x8 v; };
    UU be; be.u[0] = hi ? 0u : 0x3F803F80u;           // k-slots 0,1 = 1.0
    be.u[1] = 0u; be.u[2] = 0u; be.u[3] = 0u;

    #pragma unroll 1
    for (int mi = 0; mi < 4; ++mi) {
        STAGE_A(mi)
        // ext words issued early (L2-hit, consumed after kk-loop)
        size_t eb = (size_t)b * Q_ + m0 + mi * 128 + wm * 64 + l31;
        unsigned w0 = extg[eb];
        unsigned w1 = extg[eb + 32];
        __syncthreads();                  // A(mi) landed

        f32x16 acc00 = fz, acc01 = fz;    // row-group 0, col groups 0/1
        f32x16 acc10 = fz, acc11 = fz;    // row-group 1 (+32 rows)
        #pragma unroll 4
        for (int kk = 0; kk < 32; ++kk) {
            s16x8 a0 = *(const s16x8*)(ab + (arow + 2 * kk) * 16);
            s16x8 a1 = *(const s16x8*)(ab + (arow + 2 * kk) * 16 + 512);
            const char* bp = bbase + (size_t)(2 * kk + hi) * 4096;
            s16x8 b0 = *(const s16x8*)(bp);
            s16x8 b1 = *(const s16x8*)(bp + 512);     // +32 cols
            __builtin_amdgcn_s_setprio(1);
            acc00 = __builtin_amdgcn_mfma_f32_32x32x16_bf16(a0, b0, acc00, 0, 0, 0);
            acc01 = __builtin_amdgcn_mfma_f32_32x32x16_bf16(a0, b1, acc01, 0, 0, 0);
            acc10 = __builtin_amdgcn_mfma_f32_32x32x16_bf16(a1, b0, acc10, 0, 0, 0);
            acc11 = __builtin_amdgcn_mfma_f32_32x32x16_bf16(a1, b1, acc11, 0, 0, 0);
            __builtin_amdgcn_s_setprio(0);
        }
        // K-extension: fold wq (+ -inf invalid mask) into acc
        {
            UU ae0, ae1;
            ae0.u[0] = hi ? 0u : w0; ae0.u[1] = 0; ae0.u[2] = 0; ae0.u[3] = 0;
            ae1.u[0] = hi ? 0u : w1; ae1.u[1] = 0; ae1.u[2] = 0; ae1.u[3] = 0;
            acc00 = __builtin_amdgcn_mfma_f32_32x32x16_bf16(ae0.v, be.v, acc00, 0, 0, 0);
            acc01 = __builtin_amdgcn_mfma_f32_32x32x16_bf16(ae0.v, be.v, acc01, 0, 0, 0);
            acc10 = __builtin_amdgcn_mfma_f32_32x32x16_bf16(ae1.v, be.v, acc10, 0, 0, 0);
            acc11 = __builtin_amdgcn_mfma_f32_32x32x16_bf16(ae1.v, be.v, acc11, 0, 0, 0);
        }
        // register-only fold: -2*acc already includes wq and the mask
        #pragma unroll
        for (int r = 0; r < 16; ++r) {
            rm0 = fminf(rm0, fminf(-2.f * acc00[r], -2.f * acc10[r]));
            rm1 = fminf(rm1, fminf(-2.f * acc01[r], -2.f * acc11[r]));
        }
        __syncthreads();                  // all waves done with a_lds(mi)
    }

    // epilogue: + shsq (commutes with min), scale, reduce halves, atomic
    const int colg = c0 + wn * 64 + l31;
    rm0 = (rm0 + shsq[colg])      * (1.f / 512.f);
    rm1 = (rm1 + shsq[colg + 32]) * (1.f / 512.f);
    rm0 = fminf(rm0, __shfl_xor(rm0, 32, 64));
    rm1 = fminf(rm1, __shfl_xor(rm1, 32, 64));
    if (hi == 0) {
        atomicMin(&hmin[b * L_ + colg],      fenc(rm0));
        atomicMin(&hmin[b * L_ + colg + 32], fenc(rm1));
    }
}

// ---- final: gating + FC [B,L] -> [B,2] ----
__global__ __launch_bounds__(256) void k_final(const unsigned* __restrict__ hmin,
                                               const float* __restrict__ gating,
                                               const float* __restrict__ w,
                                               const float* __restrict__ bias,
                                               float* __restrict__ out) {
    const int b = blockIdx.x, t = threadIdx.x;       // 256 threads = L
    float v = fdec(hmin[b * L_ + t]);
    float g = 1.f / (1.f + __expf(-gating[t]));
    float mg = v * g;
    float p0 = mg * w[t];
    float p1 = mg * w[L_ + t];
    #pragma unroll
    for (int off = 32; off >= 1; off >>= 1) {
        p0 += __shfl_down(p0, off, 64);
        p1 += __shfl_down(p1, off, 64);
    }
    __shared__ float r0[4], r1[4];
    int wvi = t >> 6, ln = t & 63;
    if (ln == 0) { r0[wvi] = p0; r1[wvi] = p1; }
    __syncthreads();
    if (t == 0) {
        out[b * 2 + 0] = r0[0] + r0[1] + r0[2] + r0[3] + bias[0];
        out[b * 2 + 1] = r1[0] + r1[1] + r1[2] + r1[3] + bias[1];
    }
}

extern "C" void kernel_launch(void* const* d_in, const int* in_sizes, int n_in,
                              void* d_out, int out_size, void* d_ws, size_t ws_size,
                              hipStream_t stream) {
    const float* ts     = (const float*)d_in[0];
    const float* sh     = (const float*)d_in[1];
    const float* gating = (const float*)d_in[2];
    const float* fw     = (const float*)d_in[3];
    const float* fb     = (const float*)d_in[4];
    float* out = (float*)d_out;

    char* ws = (char*)d_ws;
    uint4*    tsb  = (uint4*)ws;                         // 4 MiB + 8 KB pad
    uint4*    shb2 = (uint4*)(ws + 4202496);             // 256 KiB (k-major)
    float*    shsq = (float*)(ws + 4464640);             // 1 KiB
    unsigned* hmin = (unsigned*)(ws + 4465664);          // 128 KiB
    unsigned* extg = (unsigned*)(ws + 4596736);          // 1 MiB

    k_prep<<<322, 256, 0, stream>>>(ts, sh, tsb, shb2, shsq, extg, hmin);
    dim3 grid(8, B_);
    k_main<<<grid, 256, 0, stream>>>(tsb, shb2, extg, shsq, hmin);
    k_final<<<128, 256, 0, stream>>>(hmin, gating, fw, fb, out);
}

// Round 16
// 66.117 us; speedup vs baseline: 1.1728x; 1.1728x over previous
//
#include <hip/hip_runtime.h>
#include <stdint.h>

#define B_ 128
#define Q_ 2048
#define C_ 8
#define L_ 256
#define K_ 64
#define S_ 1985            // Q - K + 1
#define KC_ 512            // K*C

typedef short s16x8 __attribute__((ext_vector_type(8)));
typedef float f32x16 __attribute__((ext_vector_type(16)));

__device__ __forceinline__ unsigned short f2bf(float f) {
    unsigned u = __float_as_uint(f);
    u += 0x7FFFu + ((u >> 16) & 1u);        // round-to-nearest-even
    return (unsigned short)(u >> 16);
}
// monotone float -> unsigned encoding (order-preserving), for atomicMin
__device__ __forceinline__ unsigned fenc(float f) {
    unsigned u = __float_as_uint(f);
    return (u & 0x80000000u) ? ~u : (u | 0x80000000u);
}
__device__ __forceinline__ float fdec(unsigned k) {
    unsigned u = (k & 0x80000000u) ? (k ^ 0x80000000u) : ~k;
    return __uint_as_float(u);
}
__device__ __forceinline__ void async_copy16(void* lds_dst, const void* g_src) {
    __builtin_amdgcn_global_load_lds(
        (const __attribute__((address_space(1))) void*)g_src,
        (__attribute__((address_space(3))) void*)lds_dst, 16, 0, 0);
}

// ---- fused prep: ts cast+window-norms | shapelet blobs+norms | init ----
__global__ __launch_bounds__(256) void k_prep(const float* __restrict__ ts,
                                              const float* __restrict__ sh,
                                              uint4* __restrict__ tsb,
                                              uint4* __restrict__ shb,
                                              float* __restrict__ shsq,
                                              unsigned* __restrict__ extg,
                                              unsigned* __restrict__ hmin) {
    __shared__ float t2[2048];
    const int bid = blockIdx.x, t = threadIdx.x;
    if (bid < 128) {
        const int b = bid;
        #pragma unroll
        for (int j = 0; j < 8; ++j) {
            int r = j * 256 + t;
            const float4* p = (const float4*)(ts + ((size_t)b * Q_ + r) * C_);
            float4 x = p[0], y = p[1];
            union { unsigned short h[8]; uint4 v; } u;
            u.h[0] = f2bf(x.x); u.h[1] = f2bf(x.y); u.h[2] = f2bf(x.z); u.h[3] = f2bf(x.w);
            u.h[4] = f2bf(y.x); u.h[5] = f2bf(y.y); u.h[6] = f2bf(y.z); u.h[7] = f2bf(y.w);
            tsb[(size_t)b * Q_ + r] = u.v;
            t2[r] = x.x*x.x + x.y*x.y + x.z*x.z + x.w*x.w
                  + y.x*y.x + y.y*y.y + y.z*y.z + y.w*y.w;
        }
        __syncthreads();
        int s0 = t * 8;
        float w = 0.f;
        if (s0 < S_) {
            #pragma unroll 16
            for (int k = 0; k < K_; ++k) w += t2[s0 + k];
        }
        #pragma unroll
        for (int j = 0; j < 8; ++j) {
            int s = s0 + j;
            unsigned word = 0x0000FF80u;              // slot0 = -inf, slot1 = 0
            if (s < S_) {
                float v = -0.5f * w;
                unsigned short hh = f2bf(v);
                float hf = __uint_as_float((unsigned)hh << 16);
                unsigned short ll = f2bf(v - hf);
                word = (unsigned)hh | ((unsigned)ll << 16);
            }
            extg[(size_t)b * Q_ + s] = word;
            if (s + K_ < Q_) w += t2[s + K_] - t2[s]; // slide window
        }
    } else if (bid < 192) {
        const int l = (bid - 128) * 4 + (t >> 6);     // shapelet index
        const int c = t & 63;                         // k16-chunk index
        const float4* p = (const float4*)(sh + (size_t)l * KC_) + c * 2;
        float4 x = p[0], y = p[1];
        union { unsigned short h[8]; uint4 v; } u;
        u.h[0] = f2bf(x.x); u.h[1] = f2bf(x.y); u.h[2] = f2bf(x.z); u.h[3] = f2bf(x.w);
        u.h[4] = f2bf(y.x); u.h[5] = f2bf(y.y); u.h[6] = f2bf(y.z); u.h[7] = f2bf(y.w);
        shb[l * 64 + c] = u.v;                        // col blob [l][chunk]
        float ss = x.x*x.x + x.y*x.y + x.z*x.z + x.w*x.w
                 + y.x*y.x + y.y*y.y + y.z*y.z + y.w*y.w;
        #pragma unroll
        for (int off = 32; off >= 1; off >>= 1) ss += __shfl_down(ss, off, 64);
        if (c == 0) shsq[l] = ss;
    } else if (bid < 194) {
        uint4 z; z.x = z.y = z.z = z.w = 0u;
        tsb[B_ * Q_ + (bid - 192) * 256 + t] = z;
    } else {
        hmin[(bid - 194) * 256 + t] = 0xFFFFFFFFu;
    }
}

// ---- main: implicit-GEMM conv + fused min-pool; 4 waves/SIMD ----
// 512-thr blocks (8 waves as 8m x 1n), wave tile 64 rows x 64 cols,
// acc 2x2 (64 AGPR; total regs ~115 <= 128 => 4 waves/SIMD at 2 blocks/CU).
// B = 64 cols x full-K (64 KB) staged ONCE per block; A single-buffered
// 576 rows (9 KB); LDS 73.8 KB -> exactly 2 blocks/CU -> 16 waves/CU.
// Grid (4 n, 128 b) = 512 long-lived blocks, 4 m-iters of 512 rows.
// LDS economy: 2A+2B b128 per 4 MFMAs = 1024 B/MFMA (~79% util cap at
// the ~100 B/cyc effective LDS pipe). wq + validity folded via the
// K-extension MFMA (extg carries -wq/2 bf16 pair; -inf marks invalid).
__global__ __launch_bounds__(512, 4) void k_main(
    const uint4* __restrict__ tsb,        // bf16 [B][Q][C] (+512 pad rows)
    const uint4* __restrict__ shb,        // bf16 [L][64] col blobs
    const unsigned* __restrict__ extg,    // [B][2048] packed (-wq/2) pairs
    const float* __restrict__ shsq,       // [L]
    unsigned*    __restrict__ hmin)       // [B][L] encoded min
{
    __shared__ uint4 b_lds[4096];         // 64 cols x 64 chunks x 16B = 64 KB
    __shared__ uint4 a_lds[576];          // 576 ts-rows x 16B = 9 KB

    const int nt   = blockIdx.x;          // 0..3
    const int b    = blockIdx.y;
    const int c0   = nt * 64;
    const int tid  = threadIdx.x;         // 0..511
    const int lane = tid & 63;
    const int wv   = tid >> 6;            // 0..7 = row group of 64
    const int l31  = lane & 31;
    const int hi   = lane >> 5;

    #define STAGE_A(mi_)                                                       \
        {                                                                      \
            const char* gA = (const char*)(tsb + (size_t)b * Q_ + (mi_) * 512);\
            async_copy16((char*)a_lds + tid * 16, gA + tid * 16);              \
            if (tid < 64)                                                      \
                async_copy16((char*)a_lds + (512 + tid) * 16,                  \
                             gA + (512 + tid) * 16);                           \
        }

    // stage B once: 64 cols x 1 KB, 8 cols per wave; stored chunk = src ^ col
    #pragma unroll
    for (int it = 0; it < 8; ++it) {
        int col = wv * 8 + it;
        const char* g = (const char*)shb + (size_t)(c0 + col) * 1024
                      + ((lane ^ (col & 31)) << 4);
        async_copy16((char*)b_lds + col * 1024, g);
    }
    STAGE_A(0)
    __syncthreads();   // B + A0 landed

    const f32x16 fz = {0.f,0.f,0.f,0.f,0.f,0.f,0.f,0.f,
                       0.f,0.f,0.f,0.f,0.f,0.f,0.f,0.f};
    const float inf = __builtin_inff();
    float rm0 = inf, rm1 = inf;           // cols c0+l31 / c0+l31+32

    const char* ab   = (const char*)a_lds;
    const char* bb   = (const char*)b_lds;
    const int   arow = wv * 64 + l31 + hi;           // ts-row base in tile
    const int   bcol = l31 * 1024;                   // B col byte base

    union UU { unsigned u[4]; s16x8 v; };
    UU be; be.u[0] = hi ? 0u : 0x3F803F80u;          // k-slots 0,1 = 1.0
    be.u[1] = 0u; be.u[2] = 0u; be.u[3] = 0u;

    #pragma unroll 1
    for (int mi = 0; mi < 4; ++mi) {
        // ext words early (L2-hit; consumed after the kk-loop)
        size_t eb = (size_t)b * Q_ + mi * 512 + wv * 64 + l31;
        unsigned w0 = extg[eb];
        unsigned w1 = extg[eb + 32];

        f32x16 acc00 = fz, acc01 = fz;    // rows g0 (+0),  cols l31 / l31+32
        f32x16 acc10 = fz, acc11 = fz;    // rows g1 (+32)
        #pragma unroll 4
        for (int kk = 0; kk < 32; ++kk) {
            s16x8 a0 = *(const s16x8*)(ab + (arow + 2 * kk) * 16);
            s16x8 a1 = *(const s16x8*)(ab + (arow + 2 * kk) * 16 + 512);
            int ch = ((2 * kk + hi) ^ l31) << 4;
            s16x8 b0 = *(const s16x8*)(bb + bcol + ch);
            s16x8 b1 = *(const s16x8*)(bb + bcol + ch + 32768);  // +32 cols
            __builtin_amdgcn_s_setprio(1);
            acc00 = __builtin_amdgcn_mfma_f32_32x32x16_bf16(a0, b0, acc00, 0, 0, 0);
            acc01 = __builtin_amdgcn_mfma_f32_32x32x16_bf16(a0, b1, acc01, 0, 0, 0);
            acc10 = __builtin_amdgcn_mfma_f32_32x32x16_bf16(a1, b0, acc10, 0, 0, 0);
            acc11 = __builtin_amdgcn_mfma_f32_32x32x16_bf16(a1, b1, acc11, 0, 0, 0);
            __builtin_amdgcn_s_setprio(0);
        }
        // K-extension: fold wq (+ -inf invalid mask) into acc
        {
            UU ae0, ae1;
            ae0.u[0] = hi ? 0u : w0; ae0.u[1] = 0; ae0.u[2] = 0; ae0.u[3] = 0;
            ae1.u[0] = hi ? 0u : w1; ae1.u[1] = 0; ae1.u[2] = 0; ae1.u[3] = 0;
            acc00 = __builtin_amdgcn_mfma_f32_32x32x16_bf16(ae0.v, be.v, acc00, 0, 0, 0);
            acc01 = __builtin_amdgcn_mfma_f32_32x32x16_bf16(ae0.v, be.v, acc01, 0, 0, 0);
            acc10 = __builtin_amdgcn_mfma_f32_32x32x16_bf16(ae1.v, be.v, acc10, 0, 0, 0);
            acc11 = __builtin_amdgcn_mfma_f32_32x32x16_bf16(ae1.v, be.v, acc11, 0, 0, 0);
        }
        __syncthreads();                  // all waves done reading a_lds(mi)
        if (mi < 3) STAGE_A(mi + 1)       // issue next stage...

        // ...register-only fold overlaps the stage flight
        #pragma unroll
        for (int r = 0; r < 16; ++r) {
            rm0 = fminf(rm0, fminf(-2.f * acc00[r], -2.f * acc10[r]));
            rm1 = fminf(rm1, fminf(-2.f * acc01[r], -2.f * acc11[r]));
        }
        __syncthreads();                  // stage(mi+1) landed
    }

    // epilogue: + shsq (commutes with min), scale, reduce halves, atomic
    const int colg = c0 + l31;
    rm0 = (rm0 + shsq[colg])      * (1.f / 512.f);
    rm1 = (rm1 + shsq[colg + 32]) * (1.f / 512.f);
    rm0 = fminf(rm0, __shfl_xor(rm0, 32, 64));
    rm1 = fminf(rm1, __shfl_xor(rm1, 32, 64));
    if (hi == 0) {
        atomicMin(&hmin[b * L_ + colg],      fenc(rm0));
        atomicMin(&hmin[b * L_ + colg + 32], fenc(rm1));
    }
}

// ---- final: gating + FC [B,L] -> [B,2] ----
__global__ __launch_bounds__(256) void k_final(const unsigned* __restrict__ hmin,
                                               const float* __restrict__ gating,
                                               const float* __restrict__ w,
                                               const float* __restrict__ bias,
                                               float* __restrict__ out) {
    const int b = blockIdx.x, t = threadIdx.x;       // 256 threads = L
    float v = fdec(hmin[b * L_ + t]);
    float g = 1.f / (1.f + __expf(-gating[t]));
    float mg = v * g;
    float p0 = mg * w[t];
    float p1 = mg * w[L_ + t];
    #pragma unroll
    for (int off = 32; off >= 1; off >>= 1) {
        p0 += __shfl_down(p0, off, 64);
        p1 += __shfl_down(p1, off, 64);
    }
    __shared__ float r0[4], r1[4];
    int wvi = t >> 6, ln = t & 63;
    if (ln == 0) { r0[wvi] = p0; r1[wvi] = p1; }
    __syncthreads();
    if (t == 0) {
        out[b * 2 + 0] = r0[0] + r0[1] + r0[2] + r0[3] + bias[0];
        out[b * 2 + 1] = r1[0] + r1[1] + r1[2] + r1[3] + bias[1];
    }
}

extern "C" void kernel_launch(void* const* d_in, const int* in_sizes, int n_in,
                              void* d_out, int out_size, void* d_ws, size_t ws_size,
                              hipStream_t stream) {
    const float* ts     = (const float*)d_in[0];
    const float* sh     = (const float*)d_in[1];
    const float* gating = (const float*)d_in[2];
    const float* fw     = (const float*)d_in[3];
    const float* fb     = (const float*)d_in[4];
    float* out = (float*)d_out;

    char* ws = (char*)d_ws;
    uint4*    tsb  = (uint4*)ws;                         // 4 MiB + 8 KB pad
    uint4*    shb  = (uint4*)(ws + 4202496);             // 256 KiB (col blobs)
    float*    shsq = (float*)(ws + 4464640);             // 1 KiB
    unsigned* hmin = (unsigned*)(ws + 4465664);          // 128 KiB
    unsigned* extg = (unsigned*)(ws + 4596736);          // 1 MiB

    k_prep<<<322, 256, 0, stream>>>(ts, sh, tsb, shb, shsq, extg, hmin);
    dim3 grid(4, B_);
    k_main<<<grid, 512, 0, stream>>>(tsb, shb, extg, shsq, hmin);
    k_final<<<128, 256, 0, stream>>>(hmin, gating, fw, fb, out);
}